// Round 1
// baseline (358.585 us; speedup 1.0000x reference)
//
#include <hip/hip_runtime.h>
#include <stdint.h>

#define DD 512
#define MTOT 32768  // B*N = 8*4096

typedef float f32x4 __attribute__((ext_vector_type(4)));
typedef __bf16 bf16x8 __attribute__((ext_vector_type(8)));

__device__ __forceinline__ unsigned short f2bf(float f) {
  union { float f; unsigned int u; } c; c.f = f;
  unsigned int r = c.u + 0x7fffu + ((c.u >> 16) & 1u);
  return (unsigned short)(r >> 16);
}
__device__ __forceinline__ float bf2f(unsigned short h) {
  union { unsigned int u; float f; } c; c.u = ((unsigned int)h) << 16;
  return c.f;
}

union FragU { uint4 u; bf16x8 b; };

// ---------------- weight fp32 -> bf16 ----------------
__global__ __launch_bounds__(256) void convw_k(const float* __restrict__ Wq,
    const float* __restrict__ Wk, const float* __restrict__ Wp,
    const float* __restrict__ Wf, unsigned short* __restrict__ out) {
  int i = (blockIdx.x * 256 + threadIdx.x) * 4;
  int slab = i >> 18;           // 262144 elems per weight
  int off = i & 262143;
  const float* src = slab == 0 ? Wq : slab == 1 ? Wk : slab == 2 ? Wp : Wf;
  float4 f = *(const float4*)(src + off);
  ushort4 h;
  h.x = f2bf(f.x); h.y = f2bf(f.y); h.z = f2bf(f.z); h.w = f2bf(f.w);
  *(ushort4*)(out + i) = h;
}

// ---------------- GEMM: C[m,n] = sum_k X[m,k] * W[n,k] (+epilogue) --------
// AMODE: 0 = X fp32; 1 = X bf16; 2 = X bf16 scaled by G[batch, k]
// EMODE: 0 = +bias -> bf16; 1 = +bias +Qadd -> bf16; 2 = +bias -> fp32
template<int AMODE, int EMODE>
__global__ __launch_bounds__(256) void gemm_k(const void* __restrict__ Xv,
    const unsigned short* __restrict__ W, const float* __restrict__ bias,
    const float* __restrict__ Gm, const unsigned short* __restrict__ Qadd,
    void* __restrict__ Cv) {
  constexpr int BM = 128, BK = 32, LDA = 40;  // LDA padded: 2-way LDS aliasing only
  __shared__ unsigned short As[BM * LDA];
  __shared__ unsigned short Bs[BM * LDA];
  const int tid = threadIdx.x;
  const int lane = tid & 63, wave = tid >> 6;
  const int wr = (wave >> 1) * 64, wc = (wave & 1) * 64;
  const int row0 = blockIdx.x * BM;
  const int col0 = blockIdx.y * BM;
  const int srow = tid >> 1;          // staging row 0..127
  const int skk = (tid & 1) * 16;     // staging k-segment 0/16
  const int fr = lane & 15, quad = lane >> 4;

  f32x4 acc[4][4] = {};

  const float* Gb = nullptr;
  if (AMODE == 2) Gb = Gm + (size_t)(row0 >> 12) * DD;  // 4096 rows per batch

  for (int k0 = 0; k0 < DD; k0 += BK) {
    unsigned short* adst = &As[srow * LDA + skk];
    if (AMODE == 0) {
      const float* Xr = (const float*)Xv + (size_t)(row0 + srow) * DD + k0 + skk;
#pragma unroll
      for (int q = 0; q < 4; q++) {
        float4 f = ((const float4*)Xr)[q];
        ushort4 h; h.x = f2bf(f.x); h.y = f2bf(f.y); h.z = f2bf(f.z); h.w = f2bf(f.w);
        *(ushort4*)(adst + q * 4) = h;
      }
    } else if (AMODE == 1) {
      const uint4* Xr = (const uint4*)((const unsigned short*)Xv +
                                       (size_t)(row0 + srow) * DD + k0 + skk);
      *(uint4*)adst = Xr[0];
      *(uint4*)(adst + 8) = Xr[1];
    } else {
      const unsigned short* Xr = (const unsigned short*)Xv +
                                 (size_t)(row0 + srow) * DD + k0 + skk;
      const float* Gk = Gb + k0 + skk;
#pragma unroll
      for (int q = 0; q < 4; q++) {
        ushort4 x = *(const ushort4*)(Xr + q * 4);
        float4 g = ((const float4*)Gk)[q];
        ushort4 h;
        h.x = f2bf(bf2f(x.x) * g.x);
        h.y = f2bf(bf2f(x.y) * g.y);
        h.z = f2bf(bf2f(x.z) * g.z);
        h.w = f2bf(bf2f(x.w) * g.w);
        *(ushort4*)(adst + q * 4) = h;
      }
    }
    {
      const uint4* Wr = (const uint4*)(W + (size_t)(col0 + srow) * DD + k0 + skk);
      unsigned short* bdst = &Bs[srow * LDA + skk];
      *(uint4*)bdst = Wr[0];
      *(uint4*)(bdst + 8) = Wr[1];
    }
    __syncthreads();
    bf16x8 af[4], bfr[4];
#pragma unroll
    for (int i = 0; i < 4; i++) {
      FragU u; u.u = *(const uint4*)&As[(wr + i * 16 + fr) * LDA + quad * 8];
      af[i] = u.b;
    }
#pragma unroll
    for (int j = 0; j < 4; j++) {
      FragU u; u.u = *(const uint4*)&Bs[(wc + j * 16 + fr) * LDA + quad * 8];
      bfr[j] = u.b;
    }
#pragma unroll
    for (int i = 0; i < 4; i++)
#pragma unroll
      for (int j = 0; j < 4; j++)
        acc[i][j] = __builtin_amdgcn_mfma_f32_16x16x32_bf16(af[i], bfr[j], acc[i][j], 0, 0, 0);
    __syncthreads();
  }
  // epilogue: C/D layout col=lane&15, row=(lane>>4)*4+reg
#pragma unroll
  for (int j = 0; j < 4; j++) {
    int gc = col0 + wc + j * 16 + fr;
    float bv = bias[gc];
#pragma unroll
    for (int i = 0; i < 4; i++) {
      int gr0 = row0 + wr + i * 16 + quad * 4;
#pragma unroll
      for (int r = 0; r < 4; r++) {
        size_t idx = (size_t)(gr0 + r) * DD + gc;
        float v = acc[i][j][r] + bv;
        if (EMODE == 1) v += bf2f(Qadd[idx]);
        if (EMODE <= 1) ((unsigned short*)Cv)[idx] = f2bf(v);
        else            ((float*)Cv)[idx] = v;
      }
    }
  }
}

// ---------------- row l2-norm (in place) + optional w_g dot --------------
// grid (MTOT/4, 2): y==0 -> Q (also A_raw), y==1 -> K. One wave per row.
__global__ __launch_bounds__(256) void norm_k(unsigned short* __restrict__ Q,
    unsigned short* __restrict__ K, const float* __restrict__ wg,
    float* __restrict__ Araw) {
  const int lane = threadIdx.x & 63, wave = threadIdx.x >> 6;
  const size_t row = (size_t)blockIdx.x * 4 + wave;
  unsigned short* p = (blockIdx.y == 0 ? Q : K) + row * DD + lane * 8;
  uint4 u = *(uint4*)p;
  unsigned short* hp = (unsigned short*)&u;
  float v[8];
  float ss = 0.f;
#pragma unroll
  for (int t = 0; t < 8; t++) { v[t] = bf2f(hp[t]); ss += v[t] * v[t]; }
#pragma unroll
  for (int m = 1; m < 64; m <<= 1) ss += __shfl_xor(ss, m, 64);
  float inv = 1.0f / fmaxf(sqrtf(ss), 1e-12f);
#pragma unroll
  for (int t = 0; t < 8; t++) { v[t] *= inv; hp[t] = f2bf(v[t]); }
  *(uint4*)p = u;
  if (blockIdx.y == 0) {
    const float4* wp = (const float4*)(wg + lane * 8);
    float4 w0 = wp[0], w1 = wp[1];
    float dot = v[0] * w0.x + v[1] * w0.y + v[2] * w0.z + v[3] * w0.w +
                v[4] * w1.x + v[5] * w1.y + v[6] * w1.z + v[7] * w1.w;
#pragma unroll
    for (int m = 1; m < 64; m <<= 1) dot += __shfl_xor(dot, m, 64);
    if (lane == 0) Araw[row] = dot;  // D^-0.5 scale cancels in the axis-1 l2norm
  }
}

// ---------------- per-batch ||A_raw|| -> 1/s ; zero G --------------------
__global__ __launch_bounds__(512) void reduce_s_k(const float* __restrict__ Araw,
    float* __restrict__ sinv, float* __restrict__ G) {
  const int b = blockIdx.x, t = threadIdx.x;
  G[b * DD + t] = 0.f;
  float ss = 0.f;
  for (int i = t; i < 4096; i += 512) { float v = Araw[b * 4096 + i]; ss += v * v; }
#pragma unroll
  for (int m = 1; m < 64; m <<= 1) ss += __shfl_xor(ss, m, 64);
  __shared__ float sred[8];
  if ((t & 63) == 0) sred[t >> 6] = ss;
  __syncthreads();
  if (t == 0) {
    float tot = 0.f;
    for (int i = 0; i < 8; i++) tot += sred[i];
    sinv[b] = 1.0f / fmaxf(sqrtf(tot), 1e-12f);
  }
}

// ---------------- G[b,d] = sum_n (A_raw[b,n]/s[b]) * Q[b,n,d] ------------
// grid 256 blocks (32 chunks x 8 batches) x 256 threads; atomicAdd into G.
__global__ __launch_bounds__(256) void pool_k(const float* __restrict__ Araw,
    const float* __restrict__ sinv, const unsigned short* __restrict__ Q,
    float* __restrict__ G) {
  const int b = blockIdx.x >> 5;
  const int chunk = blockIdx.x & 31;
  const int rbase = b * 4096 + chunk * 128;
  const float si = sinv[b];
  const int t = threadIdx.x;
  float a0 = 0.f, a1 = 0.f;
  for (int r = 0; r < 128; r++) {
    float w = Araw[rbase + r] * si;
    const unsigned short* qr = Q + (size_t)(rbase + r) * DD;
    a0 += w * bf2f(qr[t]);
    a1 += w * bf2f(qr[t + 256]);
  }
  atomicAdd(&G[b * DD + t], a0);
  atomicAdd(&G[b * DD + t + 256], a1);
}

extern "C" void kernel_launch(void* const* d_in, const int* in_sizes, int n_in,
                              void* d_out, int out_size, void* d_ws, size_t ws_size,
                              hipStream_t stream) {
  const float* a   = (const float*)d_in[0];
  const float* b   = (const float*)d_in[1];
  const float* Wq  = (const float*)d_in[2];
  const float* bq  = (const float*)d_in[3];
  const float* Wk  = (const float*)d_in[4];
  const float* bk  = (const float*)d_in[5];
  const float* wg  = (const float*)d_in[6];
  const float* Wp  = (const float*)d_in[7];
  const float* bp  = (const float*)d_in[8];
  const float* Wf  = (const float*)d_in[9];
  const float* bfb = (const float*)d_in[10];

  char* ws = (char*)d_ws;
  const size_t WELEM = 262144;        // 512*512
  const size_t MD = (size_t)MTOT * DD;  // 16,777,216 elems
  unsigned short* Wqb = (unsigned short*)ws;
  unsigned short* Wkb = Wqb + WELEM;
  unsigned short* Wpb = Wkb + WELEM;
  unsigned short* Wfb = Wpb + WELEM;
  unsigned short* Qb  = (unsigned short*)(ws + (size_t)2097152);
  unsigned short* Kb  = Qb + MD;
  unsigned short* O1b = Kb + MD;
  float* Araw = (float*)(ws + (size_t)2097152 + 3 * MD * 2);
  float* sinv = Araw + MTOT;
  float* G    = sinv + 64;   // padded

  convw_k<<<dim3(1024), dim3(256), 0, stream>>>(Wq, Wk, Wp, Wf, Wqb);
  gemm_k<0, 0><<<dim3(MTOT / 128, 4), dim3(256), 0, stream>>>(a, Wqb, bq, nullptr, nullptr, Qb);
  gemm_k<0, 0><<<dim3(MTOT / 128, 4), dim3(256), 0, stream>>>(b, Wkb, bk, nullptr, nullptr, Kb);
  norm_k<<<dim3(MTOT / 4, 2), dim3(256), 0, stream>>>(Qb, Kb, wg, Araw);
  reduce_s_k<<<dim3(8), dim3(512), 0, stream>>>(Araw, sinv, G);
  pool_k<<<dim3(256), dim3(256), 0, stream>>>(Araw, sinv, Qb, G);
  gemm_k<2, 1><<<dim3(MTOT / 128, 4), dim3(256), 0, stream>>>(Kb, Wpb, bp, G, Qb, O1b);
  gemm_k<1, 2><<<dim3(MTOT / 128, 4), dim3(256), 0, stream>>>(O1b, Wfb, bfb, nullptr, nullptr, d_out);
}

// Round 2
// 330.645 us; speedup vs baseline: 1.0845x; 1.0845x over previous
//
#include <hip/hip_runtime.h>
#include <stdint.h>

#define DD 512
#define MTOT 32768  // B*N = 8*4096

typedef float f32x4 __attribute__((ext_vector_type(4)));
typedef __bf16 bf16x8 __attribute__((ext_vector_type(8)));

static __device__ __forceinline__ unsigned short f2bf(float f) {
  union { float f; unsigned int u; } c; c.f = f;
  unsigned int r = c.u + 0x7fffu + ((c.u >> 16) & 1u);
  return (unsigned short)(r >> 16);
}
static __device__ __forceinline__ float bf2f(unsigned short h) {
  union { unsigned int u; float f; } c; c.u = ((unsigned int)h) << 16;
  return c.f;
}

union FragU { uint4 u; bf16x8 b; };

static __device__ __forceinline__ void load_lds16(const void* g, void* l) {
  __builtin_amdgcn_global_load_lds(
      (const __attribute__((address_space(1))) void*)g,
      (__attribute__((address_space(3))) void*)l, 16, 0, 0);
}

// ---------------- fp32 -> bf16, 4 elems/thread, exact grid ----------------
__global__ __launch_bounds__(256) void cvt_k(const float* __restrict__ src,
                                             unsigned short* __restrict__ dst) {
  int i = (blockIdx.x * 256 + threadIdx.x) * 4;
  float4 f = *(const float4*)(src + i);
  ushort4 h;
  h.x = f2bf(f.x); h.y = f2bf(f.y); h.z = f2bf(f.z); h.w = f2bf(f.w);
  *(ushort4*)(dst + i) = h;
}

// three 512x512 weights in one launch (768 blocks)
__global__ __launch_bounds__(256) void cvt3w_k(const float* __restrict__ W0,
    const float* __restrict__ W1, const float* __restrict__ W2,
    unsigned short* __restrict__ D0, unsigned short* __restrict__ D1,
    unsigned short* __restrict__ D2) {
  int slab = blockIdx.x >> 8;
  int off = ((blockIdx.x & 255) * 256 + threadIdx.x) * 4;
  const float* s = slab == 0 ? W0 : slab == 1 ? W1 : W2;
  unsigned short* d = slab == 0 ? D0 : slab == 1 ? D1 : D2;
  float4 f = *(const float4*)(s + off);
  ushort4 h;
  h.x = f2bf(f.x); h.y = f2bf(f.y); h.z = f2bf(f.z); h.w = f2bf(f.w);
  *(ushort4*)(d + off) = h;
}

// ---------------- W'p[b] = Wp * G[b,:] (broadcast over rows) --------------
__global__ __launch_bounds__(256) void scalew_k(const float* __restrict__ Wp,
    const float* __restrict__ G, unsigned short* __restrict__ out) {
  int i = (blockIdx.x * 256 + threadIdx.x) * 4;  // [0, 8*262144)
  int b = i >> 18;
  int rem = i & 262143;
  int d = rem & 511;
  float4 w = *(const float4*)(Wp + rem);
  float4 g = *(const float4*)(G + b * DD + d);
  ushort4 h;
  h.x = f2bf(w.x * g.x); h.y = f2bf(w.y * g.y);
  h.z = f2bf(w.z * g.z); h.w = f2bf(w.w * g.w);
  *(ushort4*)(out + i) = h;
}

// ---------------- GEMM: C[m,n] = sum_k X[m,k] * W[n,k] (+epilogue) --------
// m97 structure: 128x128 tile, BK=64, global_load_lds width-16 staging,
// XOR-swizzled LDS (kseg ^ (row&7)) so ds_read_b128 frag reads are 2-way max.
// BBATCH: W indexed per batch (row0>>12). EMODE: 0 +bias->bf16;
// 1 +bias+Qadd->bf16; 2 +bias->fp32.
template<int BBATCH, int EMODE>
__global__ __launch_bounds__(256) void gemm_k(
    const unsigned short* __restrict__ X,
    const unsigned short* __restrict__ Wb,
    const float* __restrict__ bias,
    const unsigned short* __restrict__ Qadd,
    void* __restrict__ Cv) {
  __shared__ unsigned short As[128 * 64];
  __shared__ unsigned short Bs[128 * 64];
  const int tid = threadIdx.x;
  const int lane = tid & 63, wave = tid >> 6;
  const int row0 = blockIdx.x * 128, col0 = blockIdx.y * 128;
  const unsigned short* W = Wb + (BBATCH ? (size_t)(row0 >> 12) * 262144 : 0);

  // staging: wave stages rows [wave*32, wave*32+32); inst q covers +q*8 rows.
  // lane L: row offset L>>3 (so row&7 == L>>3), stored kseg = L&7,
  // source kseg = (L&7) ^ (L>>3)   (XOR swizzle, applied on the global side)
  const int sr = lane >> 3;
  const int scol = ((lane & 7) ^ sr) * 8;
  const unsigned short* Ag = X + (size_t)(row0 + wave * 32 + sr) * DD + scol;
  const unsigned short* Bg = W + (size_t)(col0 + wave * 32 + sr) * DD + scol;
  const int ldsb = wave * 32 * 64;  // elem offset of this wave's 32-row slab

  const int fr = lane & 15, quad = lane >> 4;
  const int wr = (wave >> 1) * 64, wc = (wave & 1) * 64;
  // frag read column offset: ((kk*4 + quad) ^ (row&7)) * 8, row&7 == fr&7
  const int sw0 = ((quad ^ (fr & 7)) * 8);
  const int sw1 = (((quad + 4) ^ (fr & 7)) * 8);

  f32x4 acc[4][4] = {};

  for (int k0 = 0; k0 < DD; k0 += 64) {
#pragma unroll
    for (int q = 0; q < 4; q++) {
      load_lds16(Ag + (size_t)q * 8 * DD + k0, As + ldsb + q * 8 * 64);
      load_lds16(Bg + (size_t)q * 8 * DD + k0, Bs + ldsb + q * 8 * 64);
    }
    __syncthreads();
#pragma unroll
    for (int kk = 0; kk < 2; kk++) {
      const int sw = kk ? sw1 : sw0;
      bf16x8 af[4], bfr[4];
#pragma unroll
      for (int i = 0; i < 4; i++) {
        FragU u; u.u = *(const uint4*)&As[(wr + i * 16 + fr) * 64 + sw];
        af[i] = u.b;
      }
#pragma unroll
      for (int j = 0; j < 4; j++) {
        FragU u; u.u = *(const uint4*)&Bs[(wc + j * 16 + fr) * 64 + sw];
        bfr[j] = u.b;
      }
#pragma unroll
      for (int i = 0; i < 4; i++)
#pragma unroll
        for (int j = 0; j < 4; j++)
          acc[i][j] = __builtin_amdgcn_mfma_f32_16x16x32_bf16(af[i], bfr[j], acc[i][j], 0, 0, 0);
    }
    __syncthreads();
  }
  // epilogue: C/D layout col=lane&15, row=(lane>>4)*4+reg
#pragma unroll
  for (int j = 0; j < 4; j++) {
    int gc = col0 + wc + j * 16 + fr;
    float bv = bias[gc];
#pragma unroll
    for (int i = 0; i < 4; i++) {
      int gr0 = row0 + wr + i * 16 + quad * 4;
#pragma unroll
      for (int r = 0; r < 4; r++) {
        size_t idx = (size_t)(gr0 + r) * DD + gc;
        float v = acc[i][j][r] + bv;
        if (EMODE == 1) v += bf2f(Qadd[idx]);
        if (EMODE <= 1) ((unsigned short*)Cv)[idx] = f2bf(v);
        else            ((float*)Cv)[idx] = v;
      }
    }
  }
}

// ---------------- row l2-norm (in place) + optional w_g dot --------------
__global__ __launch_bounds__(256) void norm_k(unsigned short* __restrict__ Q,
    unsigned short* __restrict__ K, const float* __restrict__ wg,
    float* __restrict__ Araw) {
  const int lane = threadIdx.x & 63, wave = threadIdx.x >> 6;
  const size_t row = (size_t)blockIdx.x * 4 + wave;
  unsigned short* p = (blockIdx.y == 0 ? Q : K) + row * DD + lane * 8;
  uint4 u = *(uint4*)p;
  unsigned short* hp = (unsigned short*)&u;
  float v[8];
  float ss = 0.f;
#pragma unroll
  for (int t = 0; t < 8; t++) { v[t] = bf2f(hp[t]); ss += v[t] * v[t]; }
#pragma unroll
  for (int m = 1; m < 64; m <<= 1) ss += __shfl_xor(ss, m, 64);
  float inv = 1.0f / fmaxf(sqrtf(ss), 1e-12f);
#pragma unroll
  for (int t = 0; t < 8; t++) { v[t] *= inv; hp[t] = f2bf(v[t]); }
  *(uint4*)p = u;
  if (blockIdx.y == 0) {
    const float4* wp = (const float4*)(wg + lane * 8);
    float4 w0 = wp[0], w1 = wp[1];
    float dot = v[0] * w0.x + v[1] * w0.y + v[2] * w0.z + v[3] * w0.w +
                v[4] * w1.x + v[5] * w1.y + v[6] * w1.z + v[7] * w1.w;
#pragma unroll
    for (int m = 1; m < 64; m <<= 1) dot += __shfl_xor(dot, m, 64);
    if (lane == 0) Araw[row] = dot;  // D^-0.5 scale cancels in the axis-1 l2norm
  }
}

// ---------------- per-batch ||A_raw|| -> 1/s ; zero G --------------------
__global__ __launch_bounds__(512) void reduce_s_k(const float* __restrict__ Araw,
    float* __restrict__ sinv, float* __restrict__ G) {
  const int b = blockIdx.x, t = threadIdx.x;
  G[b * DD + t] = 0.f;
  float ss = 0.f;
  for (int i = t; i < 4096; i += 512) { float v = Araw[b * 4096 + i]; ss += v * v; }
#pragma unroll
  for (int m = 1; m < 64; m <<= 1) ss += __shfl_xor(ss, m, 64);
  __shared__ float sred[8];
  if ((t & 63) == 0) sred[t >> 6] = ss;
  __syncthreads();
  if (t == 0) {
    float tot = 0.f;
    for (int i = 0; i < 8; i++) tot += sred[i];
    sinv[b] = 1.0f / fmaxf(sqrtf(tot), 1e-12f);
  }
}

// ---------------- G[b,d] = sum_n (A_raw[b,n]/s[b]) * Q[b,n,d] ------------
__global__ __launch_bounds__(256) void pool_k(const float* __restrict__ Araw,
    const float* __restrict__ sinv, const unsigned short* __restrict__ Q,
    float* __restrict__ G) {
  const int b = blockIdx.x >> 5;
  const int chunk = blockIdx.x & 31;
  const int rbase = b * 4096 + chunk * 128;
  const float si = sinv[b];
  const int t = threadIdx.x;
  float a0 = 0.f, a1 = 0.f;
  for (int r = 0; r < 128; r++) {
    float w = Araw[rbase + r] * si;
    const unsigned short* qr = Q + (size_t)(rbase + r) * DD;
    a0 += w * bf2f(qr[t]);
    a1 += w * bf2f(qr[t + 256]);
  }
  atomicAdd(&G[b * DD + t], a0);
  atomicAdd(&G[b * DD + t + 256], a1);
}

extern "C" void kernel_launch(void* const* d_in, const int* in_sizes, int n_in,
                              void* d_out, int out_size, void* d_ws, size_t ws_size,
                              hipStream_t stream) {
  const float* a   = (const float*)d_in[0];
  const float* b   = (const float*)d_in[1];
  const float* Wq  = (const float*)d_in[2];
  const float* bq  = (const float*)d_in[3];
  const float* Wk  = (const float*)d_in[4];
  const float* bk  = (const float*)d_in[5];
  const float* wg  = (const float*)d_in[6];
  const float* Wp  = (const float*)d_in[7];
  const float* bp  = (const float*)d_in[8];
  const float* Wf  = (const float*)d_in[9];
  const float* bfb = (const float*)d_in[10];

  const size_t WELEM = 262144;          // 512*512
  const size_t MD = (size_t)MTOT * DD;  // 16,777,216 elems

  unsigned short* ABb = (unsigned short*)d_ws;  // a, then b, then O1 (reused)
  unsigned short* Qb  = ABb + MD;
  unsigned short* Kb  = Qb + MD;
  unsigned short* Wqb = Kb + MD;
  unsigned short* Wkb = Wqb + WELEM;
  unsigned short* Wfb = Wkb + WELEM;
  unsigned short* Wps = Wfb + WELEM;    // 8 * 262144 (per-batch scaled Wp)
  float* Araw = (float*)(Wps + 8 * WELEM);
  float* sinv = Araw + MTOT;
  float* G    = sinv + 64;

  // a -> bf16; weights -> bf16
  cvt_k<<<dim3(16384), dim3(256), 0, stream>>>(a, ABb);
  cvt3w_k<<<dim3(768), dim3(256), 0, stream>>>(Wq, Wk, Wf, Wqb, Wkb, Wfb);
  // Qraw = a*Wq^T + bq
  gemm_k<0, 0><<<dim3(256, 4), dim3(256), 0, stream>>>(ABb, Wqb, bq, nullptr, Qb);
  // b -> bf16 (reuses ABb after GEMM1 consumed it)
  cvt_k<<<dim3(16384), dim3(256), 0, stream>>>(b, ABb);
  // Kraw = b*Wk^T + bk
  gemm_k<0, 0><<<dim3(256, 4), dim3(256), 0, stream>>>(ABb, Wkb, bk, nullptr, Kb);
  // normalize Q,K in place; A_raw = Q . w_g
  norm_k<<<dim3(MTOT / 4, 2), dim3(256), 0, stream>>>(Qb, Kb, wg, Araw);
  reduce_s_k<<<dim3(8), dim3(512), 0, stream>>>(Araw, sinv, G);
  pool_k<<<dim3(256), dim3(256), 0, stream>>>(Araw, sinv, Qb, G);
  // fold G into Wp per batch (exact reassociation of (G⊙K)·Wp^T)
  scalew_k<<<dim3(2048), dim3(256), 0, stream>>>(Wp, G, Wps);
  // O1 = K*(Wp·G)^T + bp + Q   (O1 reuses ABb)
  gemm_k<1, 1><<<dim3(256, 4), dim3(256), 0, stream>>>(Kb, Wps, bp, Qb, ABb);
  // out = O1*Wf^T + bf (fp32)
  gemm_k<0, 2><<<dim3(256, 4), dim3(256), 0, stream>>>(ABb, Wfb, bfb, nullptr, d_out);
}